// Round 9
// baseline (409.739 us; speedup 1.0000x reference)
//
#include <hip/hip_runtime.h>
#include <hip/hip_fp16.h>

// N_NODES=100000, N_EDGES=50000, NNZ=1600000, dims 128->128->16, fp32 I/O.
// Message path fp16 (flat [row][128]), accumulate fp32. CSR: LDS-only counting sort.
// R15: predicated clamped gathers + v_fma_mix in agg128 (355.4 us, verified).
// R17: wave/segment predicated agg16s (neutral). edge_agg128 at 8-XCD compulsory
// fetch floor (175MB ~ 25.6MB x 8 - L3): structurally done.
// R18: (1) gemm2 fused into node_agg128 -- all lanes hold h-row post-shuffle;
// W2 in LDS at [(j*4+q)*64 + f*4+r] (2-way bank = free); deletes 51MB h16
// round-trip + 1 launch; gemm2 now uses unrounded fp32 h (more accurate).
// (2) w1t merged into hist launch. 13 -> 11 launches.

#define N_EDGES_C 50000
#define F1 128
#define F2 16
#define CHUNK 4096
#define EBIN_SHIFT 7
#define NBIN_SHIFT 8
#define EBINS 391
#define NBINS 391

typedef __attribute__((ext_vector_type(8))) _Float16 half8;
typedef __attribute__((ext_vector_type(4))) float f32x4;
typedef unsigned short ushort16_t;

// ---------------- CSR build (R12 verified) + w1t merged ----------------

__global__ __launch_bounds__(256) void hist_w1t_kernel(
    const int* __restrict__ node_idx, const int* __restrict__ edge_idx,
    int* __restrict__ echunkcnt, int* __restrict__ nchunkcnt, int nnz, int nC,
    const float* __restrict__ W1, __half* __restrict__ W1t) {
  if (blockIdx.x >= nC) {
    // w1t part: 64 blocks -> W1t16[n][k] = fp16(W1[k][n])
    int i = (blockIdx.x - nC) * 256 + threadIdx.x;   // 0..16383
    int n = i >> 7, k = i & 127;
    W1t[i] = __float2half(W1[k * 128 + n]);
    return;
  }
  __shared__ int ebc[EBINS], nbc[NBINS];
  const int t = threadIdx.x;
  for (int b = t; b < EBINS; b += 256) ebc[b] = 0;
  for (int b = t; b < NBINS; b += 256) nbc[b] = 0;
  __syncthreads();
  const int base = blockIdx.x * CHUNK;
  int end = base + CHUNK; if (end > nnz) end = nnz;
  for (int i = base + t; i < end; i += 256) {
    atomicAdd(&ebc[edge_idx[i] >> EBIN_SHIFT], 1);
    atomicAdd(&nbc[node_idx[i] >> NBIN_SHIFT], 1);
  }
  __syncthreads();
  for (int b = t; b < EBINS; b += 256) echunkcnt[b * nC + blockIdx.x] = ebc[b];
  for (int b = t; b < NBINS; b += 256) nchunkcnt[b * nC + blockIdx.x] = nbc[b];
}

__global__ __launch_bounds__(256) void cscan_p1_kernel(
    const int* __restrict__ ecc, const int* __restrict__ ncc,
    int* __restrict__ epart, int* __restrict__ npart,
    int Le, int Ln, int nbE) {
  __shared__ int red[256];
  const int t = threadIdx.x;
  const int b = blockIdx.x;
  const int* src; int L; int* dst; int bb;
  if (b < nbE) { src = ecc; L = Le; dst = epart; bb = b; }
  else         { src = ncc; L = Ln; dst = npart; bb = b - nbE; }
  int base = bb * 1024 + t * 4;
  int s = 0;
#pragma unroll
  for (int j = 0; j < 4; ++j) { int i = base + j; if (i < L) s += src[i]; }
  red[t] = s;
  __syncthreads();
  for (int d = 128; d > 0; d >>= 1) {
    if (t < d) red[t] += red[t + d];
    __syncthreads();
  }
  if (t == 0) dst[bb] = red[0];
}

__global__ __launch_bounds__(256) void cscan_p2_kernel(
    int* __restrict__ epart, int* __restrict__ npart,
    int* __restrict__ ebinbase, int* __restrict__ nbinbase,
    int nbE, int nbN, int nnz) {
  __shared__ int se[256], sn[256];
  const int t = threadIdx.x;
  se[t] = (t < nbE) ? epart[t] : 0;
  sn[t] = (t < nbN) ? npart[t] : 0;
  __syncthreads();
  for (int d = 1; d < 256; d <<= 1) {
    int ve = (t >= d) ? se[t - d] : 0;
    int vn = (t >= d) ? sn[t - d] : 0;
    __syncthreads();
    se[t] += ve; sn[t] += vn;
    __syncthreads();
  }
  if (t < nbE) epart[t] = (t > 0) ? se[t - 1] : 0;
  if (t < nbN) npart[t] = (t > 0) ? sn[t - 1] : 0;
  if (t == 0) { ebinbase[EBINS] = nnz; nbinbase[NBINS] = nnz; }
}

__global__ __launch_bounds__(256) void cscan_p3_kernel(
    const int* __restrict__ ecc, const int* __restrict__ ncc,
    const int* __restrict__ epart, const int* __restrict__ npart,
    int* __restrict__ erunoff, int* __restrict__ nrunoff,
    int* __restrict__ ebinbase, int* __restrict__ nbinbase,
    int Le, int Ln, int nbE, int nC) {
  __shared__ int red[256];
  const int t = threadIdx.x;
  const int b = blockIdx.x;
  const int* src; const int* part; int L; int* ro; int* bba; int bb;
  if (b < nbE) { src = ecc; part = epart; L = Le; ro = erunoff; bba = ebinbase; bb = b; }
  else         { src = ncc; part = npart; L = Ln; ro = nrunoff; bba = nbinbase; bb = b - nbE; }
  int base = bb * 1024 + t * 4;
  int v[4]; int s = 0;
#pragma unroll
  for (int j = 0; j < 4; ++j) { int i = base + j; v[j] = (i < L) ? src[i] : 0; s += v[j]; }
  red[t] = s;
  __syncthreads();
  for (int d = 1; d < 256; d <<= 1) {
    int x = (t >= d) ? red[t - d] : 0;
    __syncthreads();
    red[t] += x;
    __syncthreads();
  }
  int run = part[bb] + ((t > 0) ? red[t - 1] : 0);
#pragma unroll
  for (int j = 0; j < 4; ++j) {
    int i = base + j;
    if (i < L) {
      ro[i] = run;
      if (i % nC == 0) bba[i / nC] = run;
      run += v[j];
    }
  }
}

// stage: pack pairs into u32. e-side: (n<<7)|(e&127)  [17+7=24 bits]
//                             n-side: (e<<8)|(n&255)  [16+8=24 bits]

__global__ __launch_bounds__(256) void stage_kernel(
    const int* __restrict__ node_idx, const int* __restrict__ edge_idx,
    const int* __restrict__ erunoff, const int* __restrict__ nrunoff,
    unsigned* __restrict__ epairs, unsigned* __restrict__ npairs, int nnz) {
  __shared__ int ecur[EBINS], ncur[NBINS];
  const int t = threadIdx.x;
  const int nC = gridDim.x;
  for (int b = t; b < EBINS; b += 256) ecur[b] = erunoff[b * nC + blockIdx.x];
  for (int b = t; b < NBINS; b += 256) ncur[b] = nrunoff[b * nC + blockIdx.x];
  __syncthreads();
  const int base = blockIdx.x * CHUNK;
  int end = base + CHUNK; if (end > nnz) end = nnz;
  for (int i = base + t; i < end; i += 256) {
    int e = edge_idx[i];
    int n = node_idx[i];
    int p = atomicAdd(&ecur[e >> EBIN_SHIFT], 1);
    epairs[p] = ((unsigned)n << 7) | (unsigned)(e & 127);
    int q = atomicAdd(&ncur[n >> NBIN_SHIFT], 1);
    npairs[q] = ((unsigned)e << 8) | (unsigned)(n & 255);
  }
}

__global__ __launch_bounds__(256) void bin_scatter_kernel(
    const unsigned* __restrict__ epairs, const unsigned* __restrict__ npairs,
    const int* __restrict__ ebinbase, const int* __restrict__ nbinbase,
    int* __restrict__ eoff, int* __restrict__ noff,
    int* __restrict__ enbr, ushort16_t* __restrict__ nnbr,
    int n_edges, int n_nodes) {
  __shared__ int cnt[256];
  __shared__ int scn[256];
  const int bid = blockIdx.x;
  const int t = threadIdx.x;
  if (bid < EBINS) {
    const int e0 = bid << EBIN_SHIFT;
    const int ne = min(1 << EBIN_SHIFT, n_edges - e0);
    const int beg = ebinbase[bid], end = ebinbase[bid + 1];
    if (t < 128) cnt[t] = 0;
    __syncthreads();
    for (int j = beg + t; j < end; j += 256) atomicAdd(&cnt[epairs[j] & 127u], 1);
    __syncthreads();
    if (t < 128) scn[t] = cnt[t];
    __syncthreads();
    for (int d = 1; d < 128; d <<= 1) {
      int x = 0;
      if (t < 128 && t >= d) x = scn[t - d];
      __syncthreads();
      if (t < 128) scn[t] += x;
      __syncthreads();
    }
    int pos0 = 0;
    if (t < 128) {
      int excl = (t > 0) ? scn[t - 1] : 0;
      pos0 = beg + excl;
      if (t < ne) eoff[e0 + t] = pos0;
    }
    __syncthreads();
    if (t < 128) scn[t] = pos0;
    __syncthreads();
    for (int j = beg + t; j < end; j += 256) {
      unsigned p = epairs[j];
      int pos = atomicAdd(&scn[p & 127u], 1);
      enbr[pos] = (int)(p >> 7);
    }
    if (bid == EBINS - 1 && t == 0) eoff[n_edges] = end;
  } else {
    const int b = bid - EBINS;
    const int n0 = b << NBIN_SHIFT;
    const int nn = min(1 << NBIN_SHIFT, n_nodes - n0);
    const int beg = nbinbase[b], end = nbinbase[b + 1];
    cnt[t] = 0;
    __syncthreads();
    for (int j = beg + t; j < end; j += 256) atomicAdd(&cnt[npairs[j] & 255u], 1);
    __syncthreads();
    scn[t] = cnt[t];
    __syncthreads();
    for (int d = 1; d < 256; d <<= 1) {
      int x = (t >= d) ? scn[t - d] : 0;
      __syncthreads();
      scn[t] += x;
      __syncthreads();
    }
    int excl = (t > 0) ? scn[t - 1] : 0;
    int pos0 = beg + excl;
    if (t < nn) noff[n0 + t] = pos0;
    __syncthreads();
    scn[t] = pos0;
    __syncthreads();
    for (int j = beg + t; j < end; j += 256) {
      unsigned p = npairs[j];
      int pos = atomicAdd(&scn[p & 255u], 1);
      nnbr[pos] = (ushort16_t)(p >> 8);   // edge id < 50000 -> u16
    }
    if (bid == EBINS + NBINS - 1 && t == 0) noff[n_nodes] = end;
  }
}

// ---------------- GEMM1 (MFMA): xw16[M x 128] = fp16(x) @ fp16(W1) ----------------

__global__ __launch_bounds__(256) void gemm1_kernel(
    const float* __restrict__ A, const __half* __restrict__ W1t16,
    __half* __restrict__ C16, int M) {
  __shared__ _Float16 As[64 * 136];
  __shared__ _Float16 Bs[128 * 136];
  const int t = threadIdx.x;
  const int bm = blockIdx.x * 64;

#pragma unroll
  for (int i = 0; i < 8; ++i) {
    int lin = i * 256 + t;
    int row = lin >> 5;
    int c4 = lin & 31;
    int grow = bm + row;
    float4 v = make_float4(0.f, 0.f, 0.f, 0.f);
    if (grow < M) v = *(const float4*)(A + (size_t)grow * 128 + c4 * 4);
    _Float16* dst = &As[row * 136 + c4 * 4];
    dst[0] = (_Float16)v.x; dst[1] = (_Float16)v.y;
    dst[2] = (_Float16)v.z; dst[3] = (_Float16)v.w;
  }
#pragma unroll
  for (int i = 0; i < 8; ++i) {
    int lin = i * 256 + t;
    int n = lin >> 4;
    int c = lin & 15;
    *(float4*)&Bs[n * 136 + c * 8] = *(const float4*)(W1t16 + n * 128 + c * 8);
  }
  __syncthreads();

  const int w = t >> 6;
  const int lane = t & 63;
  const int l16 = lane & 15;
  const int quad = lane >> 4;

  f32x4 acc[8];
#pragma unroll
  for (int n = 0; n < 8; ++n) acc[n] = (f32x4){0.f, 0.f, 0.f, 0.f};

  const _Float16* arow = &As[(w * 16 + l16) * 136 + quad * 8];
#pragma unroll
  for (int kt = 0; kt < 4; ++kt) {
    half8 a = *(const half8*)(arow + kt * 32);
#pragma unroll
    for (int n = 0; n < 8; ++n) {
      half8 b = *(const half8*)&Bs[(n * 16 + l16) * 136 + kt * 32 + quad * 8];
      acc[n] = __builtin_amdgcn_mfma_f32_16x16x32_f16(a, b, acc[n], 0, 0, 0);
    }
  }
  __syncthreads();   // all frag reads done; reuse As as C-staging

  // C/D layout (m89-verified, dtype-independent): col=lane&15, row=quad*4+reg
#pragma unroll
  for (int n = 0; n < 8; ++n) {
#pragma unroll
    for (int r = 0; r < 4; ++r) {
      int row = w * 16 + quad * 4 + r;
      int col = n * 16 + l16;
      As[row * 136 + col] = (_Float16)acc[n][r];
    }
  }
  __syncthreads();

  // coalesced store: 64 rows x 16 chunks of 16B = 1024 / 256 = 4 iters
#pragma unroll
  for (int i = 0; i < 4; ++i) {
    int lin = i * 256 + t;
    int row = lin >> 4;
    int c = lin & 15;
    int grow = bm + row;
    if (grow < M)
      *(float4*)(C16 + (size_t)grow * 128 + c * 8) = *(const float4*)&As[row * 136 + c * 8];
  }
}

// ---------------- F=128 aggregation: predicated clamped gathers (R15) ----------------

__device__ __forceinline__ void acc_mixw(float* ax, f32x4 v, float wt) {
  const unsigned* w = (const unsigned*)&v;
#pragma unroll
  for (int q = 0; q < 4; ++q) {
    asm("v_fma_mix_f32 %0, %1, %2, %0 op_sel:[0,0,0] op_sel_hi:[1,0,0]"
        : "+v"(ax[2 * q]) : "v"(w[q]), "v"(wt));
    asm("v_fma_mix_f32 %0, %1, %2, %0 op_sel:[1,0,0] op_sel_hi:[1,0,0]"
        : "+v"(ax[2 * q + 1]) : "v"(w[q]), "v"(wt));
  }
}

__device__ __forceinline__ void acc_mix1(float& alo, float& ahi, unsigned u, float wt) {
  asm("v_fma_mix_f32 %0, %1, %2, %0 op_sel:[0,0,0] op_sel_hi:[1,0,0]"
      : "+v"(alo) : "v"(u), "v"(wt));
  asm("v_fma_mix_f32 %0, %1, %2, %0 op_sel:[1,0,0] op_sel_hi:[1,0,0]"
      : "+v"(ahi) : "v"(u), "v"(wt));
}

// edge agg: mean degree 32 -> depth 8 (stride 32 over 4 r-lanes)
__global__ __launch_bounds__(256) void edge_agg128_kernel(
    const f32x4* __restrict__ feat,
    const int* __restrict__ nbr, const int* __restrict__ off,
    float4* __restrict__ outf, int nseg) {
  int w = (blockIdx.x * 256 + threadIdx.x) >> 6;
  if (w >= nseg) return;
  const int lane = threadIdx.x & 63;
  const int r = lane >> 4;
  const int f = lane & 15;
  int beg = off[w], end = off[w + 1];
  const int kl = end - 1;
  float ax[8];
#pragma unroll
  for (int i = 0; i < 8; ++i) ax[i] = 0.f;
  for (int k = beg + r; k < end; k += 32) {
    int k1 = min(k + 4, kl),  k2 = min(k + 8, kl),  k3 = min(k + 12, kl);
    int k4 = min(k + 16, kl), k5 = min(k + 20, kl), k6 = min(k + 24, kl), k7 = min(k + 28, kl);
    float w1 = (k + 4 <= kl) ? 1.f : 0.f;
    float w2 = (k + 8 <= kl) ? 1.f : 0.f;
    float w3 = (k + 12 <= kl) ? 1.f : 0.f;
    float w4 = (k + 16 <= kl) ? 1.f : 0.f;
    float w5 = (k + 20 <= kl) ? 1.f : 0.f;
    float w6 = (k + 24 <= kl) ? 1.f : 0.f;
    float w7 = (k + 28 <= kl) ? 1.f : 0.f;
    int n0 = nbr[k],  n1 = nbr[k1], n2 = nbr[k2], n3 = nbr[k3];
    int n4 = nbr[k4], n5 = nbr[k5], n6 = nbr[k6], n7 = nbr[k7];
    f32x4 v0 = feat[(size_t)n0 * 16 + f];
    f32x4 v1 = feat[(size_t)n1 * 16 + f];
    f32x4 v2 = feat[(size_t)n2 * 16 + f];
    f32x4 v3 = feat[(size_t)n3 * 16 + f];
    f32x4 v4 = feat[(size_t)n4 * 16 + f];
    f32x4 v5 = feat[(size_t)n5 * 16 + f];
    f32x4 v6 = feat[(size_t)n6 * 16 + f];
    f32x4 v7 = feat[(size_t)n7 * 16 + f];
    asm volatile("" :: "v"(v0), "v"(v1), "v"(v2), "v"(v3),
                       "v"(v4), "v"(v5), "v"(v6), "v"(v7));
    acc_mixw(ax, v0, 1.f); acc_mixw(ax, v1, w1);
    acc_mixw(ax, v2, w2);  acc_mixw(ax, v3, w3);
    acc_mixw(ax, v4, w4);  acc_mixw(ax, v5, w5);
    acc_mixw(ax, v6, w6);  acc_mixw(ax, v7, w7);
  }
#pragma unroll
  for (int i = 0; i < 8; ++i) {
    ax[i] += __shfl_xor(ax[i], 16, 64);
    ax[i] += __shfl_xor(ax[i], 32, 64);
  }
  if (r == 0) {
    float inv = (end > beg) ? 1.f / (float)(end - beg) : 0.f;
    union { float4 f4; __half2 h[4]; } u;
#pragma unroll
    for (int q = 0; q < 4; ++q)
      u.h[q] = __floats2half2_rn(ax[2 * q] * inv, ax[2 * q + 1] * inv);
    outf[(size_t)w * 16 + f] = u.f4;
  }
}

// node agg + fused gemm2: mean degree 16 -> depth 4; after shuffle-reduce all
// lanes hold the h-row slice -> compute h@W2 in-register (W2 staged in LDS,
// slot layout (j*4+q)*64 + f*4+r: 64 distinct slots/read = 2-way bank = free).
__global__ __launch_bounds__(256) void node_agg128_fused_kernel(
    const f32x4* __restrict__ feat,
    const ushort16_t* __restrict__ nbr, const int* __restrict__ off,
    const float* __restrict__ bias,      // b1 [128]
    const float* __restrict__ W2,        // [128][16] fp32
    __half* __restrict__ out16,          // hw216 [nseg][16]
    int nseg) {
  __shared__ float w2s[2048];
  const int t = threadIdx.x;
#pragma unroll
  for (int i = 0; i < 8; ++i) {
    int lin = i * 256 + t;          // (j*4+q)*64 + f*4+r
    int plane = lin >> 6;
    int slot  = lin & 63;
    int j = plane >> 2, q = plane & 3;
    int ff = slot >> 2, rr = slot & 3;
    w2s[lin] = W2[(ff * 8 + j) * 16 + rr * 4 + q];
  }
  __syncthreads();

  int w = (blockIdx.x * 256 + threadIdx.x) >> 6;
  if (w >= nseg) return;
  const int lane = threadIdx.x & 63;
  const int r = lane >> 4;
  const int f = lane & 15;
  int beg = off[w], end = off[w + 1];
  const int kl = end - 1;
  float ax[8];
#pragma unroll
  for (int i = 0; i < 8; ++i) ax[i] = 0.f;
  for (int k = beg + r; k < end; k += 16) {
    int k1 = min(k + 4, kl), k2 = min(k + 8, kl), k3 = min(k + 12, kl);
    float w1 = (k + 4 <= kl) ? 1.f : 0.f;
    float w2 = (k + 8 <= kl) ? 1.f : 0.f;
    float w3 = (k + 12 <= kl) ? 1.f : 0.f;
    int e0 = nbr[k], e1 = nbr[k1], e2 = nbr[k2], e3 = nbr[k3];
    f32x4 v0 = feat[(size_t)e0 * 16 + f];
    f32x4 v1 = feat[(size_t)e1 * 16 + f];
    f32x4 v2 = feat[(size_t)e2 * 16 + f];
    f32x4 v3 = feat[(size_t)e3 * 16 + f];
    asm volatile("" :: "v"(v0), "v"(v1), "v"(v2), "v"(v3));
    acc_mixw(ax, v0, 1.f); acc_mixw(ax, v1, w1);
    acc_mixw(ax, v2, w2);  acc_mixw(ax, v3, w3);
  }
#pragma unroll
  for (int i = 0; i < 8; ++i) {
    ax[i] += __shfl_xor(ax[i], 16, 64);
    ax[i] += __shfl_xor(ax[i], 32, 64);
  }
  // all lanes: h[j] = relu(mean + bias), fp32 (unrounded -> more accurate gemm2)
  float inv = (end > beg) ? 1.f / (float)(end - beg) : 0.f;
  float4 blo = ((const float4*)bias)[2 * f];
  float4 bhi = ((const float4*)bias)[2 * f + 1];
  float bb[8] = {blo.x, blo.y, blo.z, blo.w, bhi.x, bhi.y, bhi.z, bhi.w};
  float h[8];
#pragma unroll
  for (int j = 0; j < 8; ++j) h[j] = fmaxf(ax[j] * inv + bb[j], 0.f);
  // partial[q] = sum_j h[j] * W2[f*8+j][r*4+q]
  float p0 = 0.f, p1 = 0.f, p2 = 0.f, p3 = 0.f;
#pragma unroll
  for (int j = 0; j < 8; ++j) {
    const float* base = &w2s[j * 256 + f * 4 + r];
    p0 = fmaf(h[j], base[0],   p0);
    p1 = fmaf(h[j], base[64],  p1);
    p2 = fmaf(h[j], base[128], p2);
    p3 = fmaf(h[j], base[192], p3);
  }
  // reduce over f (16 lanes within quarter)
#pragma unroll
  for (int m = 1; m < 16; m <<= 1) {
    p0 += __shfl_xor(p0, m, 64);
    p1 += __shfl_xor(p1, m, 64);
    p2 += __shfl_xor(p2, m, 64);
    p3 += __shfl_xor(p3, m, 64);
  }
  if (f == 0) {
    __half2* op = (__half2*)(out16 + (size_t)w * 16 + r * 4);
    op[0] = __floats2half2_rn(p0, p1);
    op[1] = __floats2half2_rn(p2, p3);
  }
}

// ---------------- F=16 aggregation (R17: wave/segment, predicated depth-4) ----------

__global__ __launch_bounds__(256) void edge_agg16_kernel(
    const unsigned* __restrict__ feat,   // hw216 as u32 [n_nodes][8]
    const int* __restrict__ nbr, const int* __restrict__ off,
    float* __restrict__ outf, int nseg) {
  int w = (blockIdx.x * 256 + threadIdx.x) >> 6;
  if (w >= nseg) return;
  const int lane = threadIdx.x & 63;
  const int r = lane >> 3;
  const int f = lane & 7;
  int beg = off[w], end = off[w + 1];
  const int kl = end - 1;
  float a0 = 0.f, a1 = 0.f;
  for (int k = beg + r; k < end; k += 32) {
    int k1 = min(k + 8, kl), k2 = min(k + 16, kl), k3 = min(k + 24, kl);
    float w1 = (k + 8 <= kl) ? 1.f : 0.f;
    float w2 = (k + 16 <= kl) ? 1.f : 0.f;
    float w3 = (k + 24 <= kl) ? 1.f : 0.f;
    int n0 = nbr[k], n1 = nbr[k1], n2 = nbr[k2], n3 = nbr[k3];
    unsigned u0 = feat[(size_t)n0 * 8 + f];
    unsigned u1 = feat[(size_t)n1 * 8 + f];
    unsigned u2 = feat[(size_t)n2 * 8 + f];
    unsigned u3 = feat[(size_t)n3 * 8 + f];
    asm volatile("" :: "v"(u0), "v"(u1), "v"(u2), "v"(u3));
    acc_mix1(a0, a1, u0, 1.f); acc_mix1(a0, a1, u1, w1);
    acc_mix1(a0, a1, u2, w2);  acc_mix1(a0, a1, u3, w3);
  }
  a0 += __shfl_xor(a0, 8, 64);  a1 += __shfl_xor(a1, 8, 64);
  a0 += __shfl_xor(a0, 16, 64); a1 += __shfl_xor(a1, 16, 64);
  a0 += __shfl_xor(a0, 32, 64); a1 += __shfl_xor(a1, 32, 64);
  if (r == 0) {
    float inv = (end > beg) ? 1.f / (float)(end - beg) : 0.f;
    ((float2*)outf)[(size_t)w * 8 + f] = make_float2(a0 * inv, a1 * inv);
  }
}

__global__ __launch_bounds__(256) void node_agg16_kernel(
    const float* __restrict__ feat,      // ef2 [n_edges][16]
    const ushort16_t* __restrict__ nbr, const int* __restrict__ off,
    const float* __restrict__ bias,
    float* __restrict__ outf, int nseg) {
  int w = (blockIdx.x * 256 + threadIdx.x) >> 6;
  if (w >= nseg) return;
  const int lane = threadIdx.x & 63;
  const int r = lane >> 4;
  const int f = lane & 15;
  int beg = off[w], end = off[w + 1];
  const int kl = end - 1;
  float a = 0.f;
  for (int k = beg + r; k < end; k += 16) {
    int k1 = min(k + 4, kl), k2 = min(k + 8, kl), k3 = min(k + 12, kl);
    float w1 = (k + 4 <= kl) ? 1.f : 0.f;
    float w2 = (k + 8 <= kl) ? 1.f : 0.f;
    float w3 = (k + 12 <= kl) ? 1.f : 0.f;
    int e0 = nbr[k], e1 = nbr[k1], e2 = nbr[k2], e3 = nbr[k3];
    float v0 = feat[(size_t)e0 * 16 + f];
    float v1 = feat[(size_t)e1 * 16 + f];
    float v2 = feat[(size_t)e2 * 16 + f];
    float v3 = feat[(size_t)e3 * 16 + f];
    asm volatile("" :: "v"(v0), "v"(v1), "v"(v2), "v"(v3));
    a += v0;
    a = fmaf(v1, w1, a);
    a = fmaf(v2, w2, a);
    a = fmaf(v3, w3, a);
  }
  a += __shfl_xor(a, 16, 64);
  a += __shfl_xor(a, 32, 64);
  if (r == 0) {
    float inv = (end > beg) ? 1.f / (float)(end - beg) : 0.f;
    outf[(size_t)w * 16 + f] = a * inv + bias[f];
  }
}

// ---------------- launch ----------------

extern "C" void kernel_launch(void* const* d_in, const int* in_sizes, int n_in,
                              void* d_out, int out_size, void* d_ws, size_t ws_size,
                              hipStream_t stream) {
  const float* x        = (const float*)d_in[0];
  const int*   node_idx = (const int*)d_in[1];
  const int*   edge_idx = (const int*)d_in[2];
  const float* W1 = (const float*)d_in[4];
  const float* b1 = (const float*)d_in[5];
  const float* W2 = (const float*)d_in[6];
  const float* b2 = (const float*)d_in[7];
  float* out = (float*)d_out;

  const int n_nodes = in_sizes[0] / F1;  // 100000
  const int nnz     = in_sizes[1];       // 1600000
  const int n_edges = N_EDGES_C;         // 50000
  const int nC      = (nnz + CHUNK - 1) / CHUNK;   // 391
  const int Le      = EBINS * nC;
  const int Ln      = NBINS * nC;
  const int nbE     = (Le + 1023) / 1024;
  const int nbN     = (Ln + 1023) / 1024;

  char* ws = (char*)d_ws;
  unsigned* epairs = (unsigned*)(ws + 0);        //  6.4M transient (packed u32)
  unsigned* npairs = (unsigned*)(ws + 6400000);  //  6.4M transient (packed u32)
  __half*  xw16   = (__half*)(ws + 25600000);    // 25.6M flat
  __half*  ef16   = (__half*)(ws + 51200000);    // 12.8M flat
  __half*  hw216  = (__half*)(ws + 64000000);    //  3.2M fp16
  float*   ef2    = (float*)(ws + 70400000);     //  3.2M
  int*     enbr   = (int*)(ws + 73600000);       //  6.4M (node ids)
  ushort16_t* nnbr16 = (ushort16_t*)(ws + 80000000); // 3.2M (edge ids, u16)
  int*     eoff   = (int*)(ws + 86400000);
  int*     noff   = (int*)(ws + 86600008);
  int*     echunkcnt = (int*)(ws + 87000016);
  int*     nchunkcnt = (int*)(ws + 87611540);
  int*     erunoff   = (int*)(ws + 88223064);
  int*     nrunoff   = (int*)(ws + 88834588);
  int*     ebinbase  = (int*)(ws + 89446112);
  int*     nbinbase  = (int*)(ws + 89447680);
  int*     epart     = (int*)(ws + 89449248);
  int*     npart     = (int*)(ws + 89450272);
  __half*  w1t16     = (__half*)(ws + 89451520); // 32,768 -> end 89,484,288

  hist_w1t_kernel<<<nC + 64, 256, 0, stream>>>(node_idx, edge_idx,
                                               echunkcnt, nchunkcnt, nnz, nC,
                                               W1, w1t16);
  cscan_p1_kernel<<<nbE + nbN, 256, 0, stream>>>(echunkcnt, nchunkcnt,
                                                 epart, npart, Le, Ln, nbE);
  cscan_p2_kernel<<<1, 256, 0, stream>>>(epart, npart, ebinbase, nbinbase,
                                         nbE, nbN, nnz);
  cscan_p3_kernel<<<nbE + nbN, 256, 0, stream>>>(echunkcnt, nchunkcnt,
                                                 epart, npart, erunoff, nrunoff,
                                                 ebinbase, nbinbase, Le, Ln, nbE, nC);
  stage_kernel<<<nC, 256, 0, stream>>>(node_idx, edge_idx, erunoff, nrunoff,
                                       epairs, npairs, nnz);
  bin_scatter_kernel<<<EBINS + NBINS, 256, 0, stream>>>(epairs, npairs,
                                                        ebinbase, nbinbase,
                                                        eoff, noff, enbr, nnbr16,
                                                        n_edges, n_nodes);

  // layer 1 (fp16 flat message path)
  gemm1_kernel<<<(n_nodes + 63) / 64, 256, 0, stream>>>(x, w1t16, xw16, n_nodes);
  edge_agg128_kernel<<<(n_edges * 64 + 255) / 256, 256, 0, stream>>>(
      (const f32x4*)xw16, enbr, eoff, (float4*)ef16, n_edges);
  node_agg128_fused_kernel<<<(n_nodes * 64 + 255) / 256, 256, 0, stream>>>(
      (const f32x4*)ef16, nnbr16, noff, b1, W2, hw216, n_nodes);

  // layer 2 (gemm2 fused above)
  edge_agg16_kernel<<<(n_edges * 64 + 255) / 256, 256, 0, stream>>>(
      (const unsigned*)hw216, enbr, eoff, ef2, n_edges);
  node_agg16_kernel<<<(n_nodes * 64 + 255) / 256, 256, 0, stream>>>(
      ef2, nnbr16, noff, b2, out, n_nodes);
}

// Round 10
// 363.947 us; speedup vs baseline: 1.1258x; 1.1258x over previous
//
#include <hip/hip_runtime.h>
#include <hip/hip_fp16.h>

// N_NODES=100000, N_EDGES=50000, NNZ=1600000, dims 128->128->16, fp32 I/O.
// Message path fp16 (flat [row][128]), accumulate fp32. CSR: LDS-only counting sort.
// R15: predicated clamped gathers + v_fma_mix in agg128 (355.4 us, verified).
// R18 POST-MORTEM: gemm2-fusion into node_agg regressed 2.6x (LDS epilogue on
// the gather critical path, 6.4M bank conflicts) -- REVERTED. Keep w1t+hist merge.
// R19: stage and gemm1 are independent -> co-launched as one kernel (block-range
// split, shared 52KB LDS buffer): gemm1's streaming hides under stage's
// scattered writes; 13 -> 11 launches. All verified inner loops untouched.

#define N_EDGES_C 50000
#define F1 128
#define F2 16
#define CHUNK 4096
#define EBIN_SHIFT 7
#define NBIN_SHIFT 8
#define EBINS 391
#define NBINS 391

typedef __attribute__((ext_vector_type(8))) _Float16 half8;
typedef __attribute__((ext_vector_type(4))) float f32x4;
typedef unsigned short ushort16_t;

// ---------------- CSR build (R12 verified) + w1t merged ----------------

__global__ __launch_bounds__(256) void hist_w1t_kernel(
    const int* __restrict__ node_idx, const int* __restrict__ edge_idx,
    int* __restrict__ echunkcnt, int* __restrict__ nchunkcnt, int nnz, int nC,
    const float* __restrict__ W1, __half* __restrict__ W1t) {
  if (blockIdx.x >= nC) {
    int i = (blockIdx.x - nC) * 256 + threadIdx.x;   // 0..16383
    int n = i >> 7, k = i & 127;
    W1t[i] = __float2half(W1[k * 128 + n]);
    return;
  }
  __shared__ int ebc[EBINS], nbc[NBINS];
  const int t = threadIdx.x;
  for (int b = t; b < EBINS; b += 256) ebc[b] = 0;
  for (int b = t; b < NBINS; b += 256) nbc[b] = 0;
  __syncthreads();
  const int base = blockIdx.x * CHUNK;
  int end = base + CHUNK; if (end > nnz) end = nnz;
  for (int i = base + t; i < end; i += 256) {
    atomicAdd(&ebc[edge_idx[i] >> EBIN_SHIFT], 1);
    atomicAdd(&nbc[node_idx[i] >> NBIN_SHIFT], 1);
  }
  __syncthreads();
  for (int b = t; b < EBINS; b += 256) echunkcnt[b * nC + blockIdx.x] = ebc[b];
  for (int b = t; b < NBINS; b += 256) nchunkcnt[b * nC + blockIdx.x] = nbc[b];
}

__global__ __launch_bounds__(256) void cscan_p1_kernel(
    const int* __restrict__ ecc, const int* __restrict__ ncc,
    int* __restrict__ epart, int* __restrict__ npart,
    int Le, int Ln, int nbE) {
  __shared__ int red[256];
  const int t = threadIdx.x;
  const int b = blockIdx.x;
  const int* src; int L; int* dst; int bb;
  if (b < nbE) { src = ecc; L = Le; dst = epart; bb = b; }
  else         { src = ncc; L = Ln; dst = npart; bb = b - nbE; }
  int base = bb * 1024 + t * 4;
  int s = 0;
#pragma unroll
  for (int j = 0; j < 4; ++j) { int i = base + j; if (i < L) s += src[i]; }
  red[t] = s;
  __syncthreads();
  for (int d = 128; d > 0; d >>= 1) {
    if (t < d) red[t] += red[t + d];
    __syncthreads();
  }
  if (t == 0) dst[bb] = red[0];
}

__global__ __launch_bounds__(256) void cscan_p2_kernel(
    int* __restrict__ epart, int* __restrict__ npart,
    int* __restrict__ ebinbase, int* __restrict__ nbinbase,
    int nbE, int nbN, int nnz) {
  __shared__ int se[256], sn[256];
  const int t = threadIdx.x;
  se[t] = (t < nbE) ? epart[t] : 0;
  sn[t] = (t < nbN) ? npart[t] : 0;
  __syncthreads();
  for (int d = 1; d < 256; d <<= 1) {
    int ve = (t >= d) ? se[t - d] : 0;
    int vn = (t >= d) ? sn[t - d] : 0;
    __syncthreads();
    se[t] += ve; sn[t] += vn;
    __syncthreads();
  }
  if (t < nbE) epart[t] = (t > 0) ? se[t - 1] : 0;
  if (t < nbN) npart[t] = (t > 0) ? sn[t - 1] : 0;
  if (t == 0) { ebinbase[EBINS] = nnz; nbinbase[NBINS] = nnz; }
}

__global__ __launch_bounds__(256) void cscan_p3_kernel(
    const int* __restrict__ ecc, const int* __restrict__ ncc,
    const int* __restrict__ epart, const int* __restrict__ npart,
    int* __restrict__ erunoff, int* __restrict__ nrunoff,
    int* __restrict__ ebinbase, int* __restrict__ nbinbase,
    int Le, int Ln, int nbE, int nC) {
  __shared__ int red[256];
  const int t = threadIdx.x;
  const int b = blockIdx.x;
  const int* src; const int* part; int L; int* ro; int* bba; int bb;
  if (b < nbE) { src = ecc; part = epart; L = Le; ro = erunoff; bba = ebinbase; bb = b; }
  else         { src = ncc; part = npart; L = Ln; ro = nrunoff; bba = nbinbase; bb = b - nbE; }
  int base = bb * 1024 + t * 4;
  int v[4]; int s = 0;
#pragma unroll
  for (int j = 0; j < 4; ++j) { int i = base + j; v[j] = (i < L) ? src[i] : 0; s += v[j]; }
  red[t] = s;
  __syncthreads();
  for (int d = 1; d < 256; d <<= 1) {
    int x = (t >= d) ? red[t - d] : 0;
    __syncthreads();
    red[t] += x;
    __syncthreads();
  }
  int run = part[bb] + ((t > 0) ? red[t - 1] : 0);
#pragma unroll
  for (int j = 0; j < 4; ++j) {
    int i = base + j;
    if (i < L) {
      ro[i] = run;
      if (i % nC == 0) bba[i / nC] = run;
      run += v[j];
    }
  }
}

// ---------------- merged stage + gemm1 (independent work, one launch) ----------
// blocks [0, nC): stage (pack pairs, LDS cursors)
// blocks [nC, nC+gemmBlocks): gemm1 MFMA tile (R15-verified code, offset bid)
// shared buffer 52224B = max(gemm1 As+Bs, stage cursors)

__global__ __launch_bounds__(256) void stage_gemm1_kernel(
    const int* __restrict__ node_idx, const int* __restrict__ edge_idx,
    const int* __restrict__ erunoff, const int* __restrict__ nrunoff,
    unsigned* __restrict__ epairs, unsigned* __restrict__ npairs,
    int nnz, int nC,
    const float* __restrict__ A, const __half* __restrict__ W1t16,
    __half* __restrict__ C16, int M) {
  __shared__ __align__(16) char smem[52224];
  const int t = threadIdx.x;

  if (blockIdx.x < nC) {
    // ---- stage ----
    int* ecur = (int*)smem;
    int* ncur = (int*)(smem + EBINS * 4);
    for (int b = t; b < EBINS; b += 256) ecur[b] = erunoff[b * nC + blockIdx.x];
    for (int b = t; b < NBINS; b += 256) ncur[b] = nrunoff[b * nC + blockIdx.x];
    __syncthreads();
    const int base = blockIdx.x * CHUNK;
    int end = base + CHUNK; if (end > nnz) end = nnz;
    for (int i = base + t; i < end; i += 256) {
      int e = edge_idx[i];
      int n = node_idx[i];
      int p = atomicAdd(&ecur[e >> EBIN_SHIFT], 1);
      epairs[p] = ((unsigned)n << 7) | (unsigned)(e & 127);
      int q = atomicAdd(&ncur[n >> NBIN_SHIFT], 1);
      npairs[q] = ((unsigned)e << 8) | (unsigned)(n & 255);
    }
    return;
  }

  // ---- gemm1 (verified R15 tile, block offset) ----
  _Float16* As = (_Float16*)smem;                 // 64*136 halves = 17408B
  _Float16* Bs = (_Float16*)(smem + 17408);       // 128*136 halves = 34816B
  const int bm = (blockIdx.x - nC) * 64;

#pragma unroll
  for (int i = 0; i < 8; ++i) {
    int lin = i * 256 + t;
    int row = lin >> 5;
    int c4 = lin & 31;
    int grow = bm + row;
    float4 v = make_float4(0.f, 0.f, 0.f, 0.f);
    if (grow < M) v = *(const float4*)(A + (size_t)grow * 128 + c4 * 4);
    _Float16* dst = &As[row * 136 + c4 * 4];
    dst[0] = (_Float16)v.x; dst[1] = (_Float16)v.y;
    dst[2] = (_Float16)v.z; dst[3] = (_Float16)v.w;
  }
#pragma unroll
  for (int i = 0; i < 8; ++i) {
    int lin = i * 256 + t;
    int n = lin >> 4;
    int c = lin & 15;
    *(float4*)&Bs[n * 136 + c * 8] = *(const float4*)(W1t16 + n * 128 + c * 8);
  }
  __syncthreads();

  const int w = t >> 6;
  const int lane = t & 63;
  const int l16 = lane & 15;
  const int quad = lane >> 4;

  f32x4 acc[8];
#pragma unroll
  for (int n = 0; n < 8; ++n) acc[n] = (f32x4){0.f, 0.f, 0.f, 0.f};

  const _Float16* arow = &As[(w * 16 + l16) * 136 + quad * 8];
#pragma unroll
  for (int kt = 0; kt < 4; ++kt) {
    half8 a = *(const half8*)(arow + kt * 32);
#pragma unroll
    for (int n = 0; n < 8; ++n) {
      half8 b = *(const half8*)&Bs[(n * 16 + l16) * 136 + kt * 32 + quad * 8];
      acc[n] = __builtin_amdgcn_mfma_f32_16x16x32_f16(a, b, acc[n], 0, 0, 0);
    }
  }
  __syncthreads();   // all frag reads done; reuse As as C-staging

  // C/D layout (m89-verified): col=lane&15, row=quad*4+reg
#pragma unroll
  for (int n = 0; n < 8; ++n) {
#pragma unroll
    for (int r = 0; r < 4; ++r) {
      int row = w * 16 + quad * 4 + r;
      int col = n * 16 + l16;
      As[row * 136 + col] = (_Float16)acc[n][r];
    }
  }
  __syncthreads();

#pragma unroll
  for (int i = 0; i < 4; ++i) {
    int lin = i * 256 + t;
    int row = lin >> 4;
    int c = lin & 15;
    int grow = bm + row;
    if (grow < M)
      *(float4*)(C16 + (size_t)grow * 128 + c * 8) = *(const float4*)&As[row * 136 + c * 8];
  }
}

__global__ __launch_bounds__(256) void bin_scatter_kernel(
    const unsigned* __restrict__ epairs, const unsigned* __restrict__ npairs,
    const int* __restrict__ ebinbase, const int* __restrict__ nbinbase,
    int* __restrict__ eoff, int* __restrict__ noff,
    int* __restrict__ enbr, ushort16_t* __restrict__ nnbr,
    int n_edges, int n_nodes) {
  __shared__ int cnt[256];
  __shared__ int scn[256];
  const int bid = blockIdx.x;
  const int t = threadIdx.x;
  if (bid < EBINS) {
    const int e0 = bid << EBIN_SHIFT;
    const int ne = min(1 << EBIN_SHIFT, n_edges - e0);
    const int beg = ebinbase[bid], end = ebinbase[bid + 1];
    if (t < 128) cnt[t] = 0;
    __syncthreads();
    for (int j = beg + t; j < end; j += 256) atomicAdd(&cnt[epairs[j] & 127u], 1);
    __syncthreads();
    if (t < 128) scn[t] = cnt[t];
    __syncthreads();
    for (int d = 1; d < 128; d <<= 1) {
      int x = 0;
      if (t < 128 && t >= d) x = scn[t - d];
      __syncthreads();
      if (t < 128) scn[t] += x;
      __syncthreads();
    }
    int pos0 = 0;
    if (t < 128) {
      int excl = (t > 0) ? scn[t - 1] : 0;
      pos0 = beg + excl;
      if (t < ne) eoff[e0 + t] = pos0;
    }
    __syncthreads();
    if (t < 128) scn[t] = pos0;
    __syncthreads();
    for (int j = beg + t; j < end; j += 256) {
      unsigned p = epairs[j];
      int pos = atomicAdd(&scn[p & 127u], 1);
      enbr[pos] = (int)(p >> 7);
    }
    if (bid == EBINS - 1 && t == 0) eoff[n_edges] = end;
  } else {
    const int b = bid - EBINS;
    const int n0 = b << NBIN_SHIFT;
    const int nn = min(1 << NBIN_SHIFT, n_nodes - n0);
    const int beg = nbinbase[b], end = nbinbase[b + 1];
    cnt[t] = 0;
    __syncthreads();
    for (int j = beg + t; j < end; j += 256) atomicAdd(&cnt[npairs[j] & 255u], 1);
    __syncthreads();
    scn[t] = cnt[t];
    __syncthreads();
    for (int d = 1; d < 256; d <<= 1) {
      int x = (t >= d) ? scn[t - d] : 0;
      __syncthreads();
      scn[t] += x;
      __syncthreads();
    }
    int excl = (t > 0) ? scn[t - 1] : 0;
    int pos0 = beg + excl;
    if (t < nn) noff[n0 + t] = pos0;
    __syncthreads();
    scn[t] = pos0;
    __syncthreads();
    for (int j = beg + t; j < end; j += 256) {
      unsigned p = npairs[j];
      int pos = atomicAdd(&scn[p & 255u], 1);
      nnbr[pos] = (ushort16_t)(p >> 8);   // edge id < 50000 -> u16
    }
    if (bid == EBINS + NBINS - 1 && t == 0) noff[n_nodes] = end;
  }
}

// ---------------- F=128 aggregation: predicated clamped gathers (R15) ----------------

__device__ __forceinline__ void acc_mixw(float* ax, f32x4 v, float wt) {
  const unsigned* w = (const unsigned*)&v;
#pragma unroll
  for (int q = 0; q < 4; ++q) {
    asm("v_fma_mix_f32 %0, %1, %2, %0 op_sel:[0,0,0] op_sel_hi:[1,0,0]"
        : "+v"(ax[2 * q]) : "v"(w[q]), "v"(wt));
    asm("v_fma_mix_f32 %0, %1, %2, %0 op_sel:[1,0,0] op_sel_hi:[1,0,0]"
        : "+v"(ax[2 * q + 1]) : "v"(w[q]), "v"(wt));
  }
}

__device__ __forceinline__ void acc_mix1(float& alo, float& ahi, unsigned u, float wt) {
  asm("v_fma_mix_f32 %0, %1, %2, %0 op_sel:[0,0,0] op_sel_hi:[1,0,0]"
      : "+v"(alo) : "v"(u), "v"(wt));
  asm("v_fma_mix_f32 %0, %1, %2, %0 op_sel:[1,0,0] op_sel_hi:[1,0,0]"
      : "+v"(ahi) : "v"(u), "v"(wt));
}

// edge agg: mean degree 32 -> depth 8 (stride 32 over 4 r-lanes)
__global__ __launch_bounds__(256) void edge_agg128_kernel(
    const f32x4* __restrict__ feat,
    const int* __restrict__ nbr, const int* __restrict__ off,
    float4* __restrict__ outf, int nseg) {
  int w = (blockIdx.x * 256 + threadIdx.x) >> 6;
  if (w >= nseg) return;
  const int lane = threadIdx.x & 63;
  const int r = lane >> 4;
  const int f = lane & 15;
  int beg = off[w], end = off[w + 1];
  const int kl = end - 1;
  float ax[8];
#pragma unroll
  for (int i = 0; i < 8; ++i) ax[i] = 0.f;
  for (int k = beg + r; k < end; k += 32) {
    int k1 = min(k + 4, kl),  k2 = min(k + 8, kl),  k3 = min(k + 12, kl);
    int k4 = min(k + 16, kl), k5 = min(k + 20, kl), k6 = min(k + 24, kl), k7 = min(k + 28, kl);
    float w1 = (k + 4 <= kl) ? 1.f : 0.f;
    float w2 = (k + 8 <= kl) ? 1.f : 0.f;
    float w3 = (k + 12 <= kl) ? 1.f : 0.f;
    float w4 = (k + 16 <= kl) ? 1.f : 0.f;
    float w5 = (k + 20 <= kl) ? 1.f : 0.f;
    float w6 = (k + 24 <= kl) ? 1.f : 0.f;
    float w7 = (k + 28 <= kl) ? 1.f : 0.f;
    int n0 = nbr[k],  n1 = nbr[k1], n2 = nbr[k2], n3 = nbr[k3];
    int n4 = nbr[k4], n5 = nbr[k5], n6 = nbr[k6], n7 = nbr[k7];
    f32x4 v0 = feat[(size_t)n0 * 16 + f];
    f32x4 v1 = feat[(size_t)n1 * 16 + f];
    f32x4 v2 = feat[(size_t)n2 * 16 + f];
    f32x4 v3 = feat[(size_t)n3 * 16 + f];
    f32x4 v4 = feat[(size_t)n4 * 16 + f];
    f32x4 v5 = feat[(size_t)n5 * 16 + f];
    f32x4 v6 = feat[(size_t)n6 * 16 + f];
    f32x4 v7 = feat[(size_t)n7 * 16 + f];
    asm volatile("" :: "v"(v0), "v"(v1), "v"(v2), "v"(v3),
                       "v"(v4), "v"(v5), "v"(v6), "v"(v7));
    acc_mixw(ax, v0, 1.f); acc_mixw(ax, v1, w1);
    acc_mixw(ax, v2, w2);  acc_mixw(ax, v3, w3);
    acc_mixw(ax, v4, w4);  acc_mixw(ax, v5, w5);
    acc_mixw(ax, v6, w6);  acc_mixw(ax, v7, w7);
  }
#pragma unroll
  for (int i = 0; i < 8; ++i) {
    ax[i] += __shfl_xor(ax[i], 16, 64);
    ax[i] += __shfl_xor(ax[i], 32, 64);
  }
  if (r == 0) {
    float inv = (end > beg) ? 1.f / (float)(end - beg) : 0.f;
    union { float4 f4; __half2 h[4]; } u;
#pragma unroll
    for (int q = 0; q < 4; ++q)
      u.h[q] = __floats2half2_rn(ax[2 * q] * inv, ax[2 * q + 1] * inv);
    outf[(size_t)w * 16 + f] = u.f4;
  }
}

// node agg: mean degree 16 -> depth 4 (stride 16 over 4 r-lanes)
__global__ __launch_bounds__(256) void node_agg128_kernel(
    const f32x4* __restrict__ feat,
    const ushort16_t* __restrict__ nbr, const int* __restrict__ off,
    const float* __restrict__ bias,
    float4* __restrict__ outf, int nseg) {
  int w = (blockIdx.x * 256 + threadIdx.x) >> 6;
  if (w >= nseg) return;
  const int lane = threadIdx.x & 63;
  const int r = lane >> 4;
  const int f = lane & 15;
  int beg = off[w], end = off[w + 1];
  const int kl = end - 1;
  float ax[8];
#pragma unroll
  for (int i = 0; i < 8; ++i) ax[i] = 0.f;
  for (int k = beg + r; k < end; k += 16) {
    int k1 = min(k + 4, kl), k2 = min(k + 8, kl), k3 = min(k + 12, kl);
    float w1 = (k + 4 <= kl) ? 1.f : 0.f;
    float w2 = (k + 8 <= kl) ? 1.f : 0.f;
    float w3 = (k + 12 <= kl) ? 1.f : 0.f;
    int e0 = nbr[k], e1 = nbr[k1], e2 = nbr[k2], e3 = nbr[k3];
    f32x4 v0 = feat[(size_t)e0 * 16 + f];
    f32x4 v1 = feat[(size_t)e1 * 16 + f];
    f32x4 v2 = feat[(size_t)e2 * 16 + f];
    f32x4 v3 = feat[(size_t)e3 * 16 + f];
    asm volatile("" :: "v"(v0), "v"(v1), "v"(v2), "v"(v3));
    acc_mixw(ax, v0, 1.f); acc_mixw(ax, v1, w1);
    acc_mixw(ax, v2, w2);  acc_mixw(ax, v3, w3);
  }
#pragma unroll
  for (int i = 0; i < 8; ++i) {
    ax[i] += __shfl_xor(ax[i], 16, 64);
    ax[i] += __shfl_xor(ax[i], 32, 64);
  }
  if (r == 0) {
    float inv = (end > beg) ? 1.f / (float)(end - beg) : 0.f;
    float4 blo = ((const float4*)bias)[2 * f];
    float4 bhi = ((const float4*)bias)[2 * f + 1];
    float bb[8] = {blo.x, blo.y, blo.z, blo.w, bhi.x, bhi.y, bhi.z, bhi.w};
    union { float4 f4; __half2 h[4]; } u;
#pragma unroll
    for (int q = 0; q < 4; ++q) {
      float hx = fmaxf(ax[2 * q] * inv + bb[2 * q], 0.f);
      float hy = fmaxf(ax[2 * q + 1] * inv + bb[2 * q + 1], 0.f);
      u.h[q] = __floats2half2_rn(hx, hy);
    }
    outf[(size_t)w * 16 + f] = u.f4;
  }
}

// ---------------- GEMM2: hw2_16[M x 16] (fp16) = h16[M x 128] @ W2[128 x 16] ----------

__global__ __launch_bounds__(256) void gemm2_kernel(
    const __half* __restrict__ H16, const float* __restrict__ W2,
    __half2* __restrict__ O16, int M) {
  __shared__ float ws2[128 * 16];
  const int t = threadIdx.x;
#pragma unroll
  for (int i = 0; i < 8; ++i) ws2[i * 256 + t] = W2[i * 256 + t];
  __syncthreads();

  int r0 = blockIdx.x * 512 + t;
  int r1 = r0 + 256;
  bool v0 = r0 < M, v1 = r1 < M;
  const __half2* h0 = (const __half2*)(H16 + (size_t)r0 * 128);
  const __half2* h1 = (const __half2*)(H16 + (size_t)r1 * 128);

  float4 acc0[4], acc1[4];
#pragma unroll
  for (int q = 0; q < 4; ++q) {
    acc0[q] = make_float4(0.f, 0.f, 0.f, 0.f);
    acc1[q] = make_float4(0.f, 0.f, 0.f, 0.f);
  }

  for (int k4 = 0; k4 < 32; ++k4) {
    float2 f00 = make_float2(0.f, 0.f), f01 = make_float2(0.f, 0.f);
    float2 f10 = make_float2(0.f, 0.f), f11 = make_float2(0.f, 0.f);
    if (v0) { f00 = __half22float2(h0[2 * k4]); f01 = __half22float2(h0[2 * k4 + 1]); }
    if (v1) { f10 = __half22float2(h1[2 * k4]); f11 = __half22float2(h1[2 * k4 + 1]); }
    const float a0s[4] = {f00.x, f00.y, f01.x, f01.y};
    const float a1s[4] = {f10.x, f10.y, f11.x, f11.y};
#pragma unroll
    for (int j = 0; j < 4; ++j) {
      int k = k4 * 4 + j;
#pragma unroll
      for (int q = 0; q < 4; ++q) {
        float4 b = *(const float4*)&ws2[k * 16 + q * 4];
        acc0[q].x = fmaf(a0s[j], b.x, acc0[q].x);
        acc0[q].y = fmaf(a0s[j], b.y, acc0[q].y);
        acc0[q].z = fmaf(a0s[j], b.z, acc0[q].z);
        acc0[q].w = fmaf(a0s[j], b.w, acc0[q].w);
        acc1[q].x = fmaf(a1s[j], b.x, acc1[q].x);
        acc1[q].y = fmaf(a1s[j], b.y, acc1[q].y);
        acc1[q].z = fmaf(a1s[j], b.z, acc1[q].z);
        acc1[q].w = fmaf(a1s[j], b.w, acc1[q].w);
      }
    }
  }
  if (v0) {
    __half2* op = O16 + (size_t)r0 * 8;
#pragma unroll
    for (int q = 0; q < 4; ++q) {
      op[q * 2]     = __floats2half2_rn(acc0[q].x, acc0[q].y);
      op[q * 2 + 1] = __floats2half2_rn(acc0[q].z, acc0[q].w);
    }
  }
  if (v1) {
    __half2* op = O16 + (size_t)r1 * 8;
#pragma unroll
    for (int q = 0; q < 4; ++q) {
      op[q * 2]     = __floats2half2_rn(acc1[q].x, acc1[q].y);
      op[q * 2 + 1] = __floats2half2_rn(acc1[q].z, acc1[q].w);
    }
  }
}

// ---------------- F=16 aggregation (R17: wave/segment, predicated depth-4) ----------

__global__ __launch_bounds__(256) void edge_agg16_kernel(
    const unsigned* __restrict__ feat,   // hw216 as u32 [n_nodes][8]
    const int* __restrict__ nbr, const int* __restrict__ off,
    float* __restrict__ outf, int nseg) {
  int w = (blockIdx.x * 256 + threadIdx.x) >> 6;
  if (w >= nseg) return;
  const int lane = threadIdx.x & 63;
  const int r = lane >> 3;
  const int f = lane & 7;
  int beg = off[w], end = off[w + 1];
  const int kl = end - 1;
  float a0 = 0.f, a1 = 0.f;
  for (int k = beg + r; k < end; k += 32) {
    int k1 = min(k + 8, kl), k2 = min(k + 16, kl), k3 = min(k + 24, kl);
    float w1 = (k + 8 <= kl) ? 1.f : 0.f;
    float w2 = (k + 16 <= kl) ? 1.f : 0.f;
    float w3 = (k + 24 <= kl) ? 1.f : 0.f;
    int n0 = nbr[k], n1 = nbr[k1], n2 = nbr[k2], n3 = nbr[k3];
    unsigned u0 = feat[(size_t)n0 * 8 + f];
    unsigned u1 = feat[(size_t)n1 * 8 + f];
    unsigned u2 = feat[(size_t)n2 * 8 + f];
    unsigned u3 = feat[(size_t)n3 * 8 + f];
    asm volatile("" :: "v"(u0), "v"(u1), "v"(u2), "v"(u3));
    acc_mix1(a0, a1, u0, 1.f); acc_mix1(a0, a1, u1, w1);
    acc_mix1(a0, a1, u2, w2);  acc_mix1(a0, a1, u3, w3);
  }
  a0 += __shfl_xor(a0, 8, 64);  a1 += __shfl_xor(a1, 8, 64);
  a0 += __shfl_xor(a0, 16, 64); a1 += __shfl_xor(a1, 16, 64);
  a0 += __shfl_xor(a0, 32, 64); a1 += __shfl_xor(a1, 32, 64);
  if (r == 0) {
    float inv = (end > beg) ? 1.f / (float)(end - beg) : 0.f;
    ((float2*)outf)[(size_t)w * 8 + f] = make_float2(a0 * inv, a1 * inv);
  }
}

__global__ __launch_bounds__(256) void node_agg16_kernel(
    const float* __restrict__ feat,      // ef2 [n_edges][16]
    const ushort16_t* __restrict__ nbr, const int* __restrict__ off,
    const float* __restrict__ bias,
    float* __restrict__ outf, int nseg) {
  int w = (blockIdx.x * 256 + threadIdx.x) >> 6;
  if (w >= nseg) return;
  const int lane = threadIdx.x & 63;
  const int r = lane >> 4;
  const int f = lane & 15;
  int beg = off[w], end = off[w + 1];
  const int kl = end - 1;
  float a = 0.f;
  for (int k = beg + r; k < end; k += 16) {
    int k1 = min(k + 4, kl), k2 = min(k + 8, kl), k3 = min(k + 12, kl);
    float w1 = (k + 4 <= kl) ? 1.f : 0.f;
    float w2 = (k + 8 <= kl) ? 1.f : 0.f;
    float w3 = (k + 12 <= kl) ? 1.f : 0.f;
    int e0 = nbr[k], e1 = nbr[k1], e2 = nbr[k2], e3 = nbr[k3];
    float v0 = feat[(size_t)e0 * 16 + f];
    float v1 = feat[(size_t)e1 * 16 + f];
    float v2 = feat[(size_t)e2 * 16 + f];
    float v3 = feat[(size_t)e3 * 16 + f];
    asm volatile("" :: "v"(v0), "v"(v1), "v"(v2), "v"(v3));
    a += v0;
    a = fmaf(v1, w1, a);
    a = fmaf(v2, w2, a);
    a = fmaf(v3, w3, a);
  }
  a += __shfl_xor(a, 16, 64);
  a += __shfl_xor(a, 32, 64);
  if (r == 0) {
    float inv = (end > beg) ? 1.f / (float)(end - beg) : 0.f;
    outf[(size_t)w * 16 + f] = a * inv + bias[f];
  }
}

// ---------------- launch ----------------

extern "C" void kernel_launch(void* const* d_in, const int* in_sizes, int n_in,
                              void* d_out, int out_size, void* d_ws, size_t ws_size,
                              hipStream_t stream) {
  const float* x        = (const float*)d_in[0];
  const int*   node_idx = (const int*)d_in[1];
  const int*   edge_idx = (const int*)d_in[2];
  const float* W1 = (const float*)d_in[4];
  const float* b1 = (const float*)d_in[5];
  const float* W2 = (const float*)d_in[6];
  const float* b2 = (const float*)d_in[7];
  float* out = (float*)d_out;

  const int n_nodes = in_sizes[0] / F1;  // 100000
  const int nnz     = in_sizes[1];       // 1600000
  const int n_edges = N_EDGES_C;         // 50000
  const int nC      = (nnz + CHUNK - 1) / CHUNK;   // 391
  const int Le      = EBINS * nC;
  const int Ln      = NBINS * nC;
  const int nbE     = (Le + 1023) / 1024;
  const int nbN     = (Ln + 1023) / 1024;

  char* ws = (char*)d_ws;
  unsigned* epairs = (unsigned*)(ws + 0);        //  6.4M transient (packed u32)
  unsigned* npairs = (unsigned*)(ws + 6400000);  //  6.4M transient (packed u32)
  __half*  h16    = (__half*)(ws + 0);           // 25.6M flat (after bin_scatter)
  __half*  xw16   = (__half*)(ws + 25600000);    // 25.6M flat
  __half*  ef16   = (__half*)(ws + 51200000);    // 12.8M flat
  __half*  hw216  = (__half*)(ws + 64000000);    //  3.2M fp16
  float*   ef2    = (float*)(ws + 70400000);     //  3.2M
  int*     enbr   = (int*)(ws + 73600000);       //  6.4M (node ids)
  ushort16_t* nnbr16 = (ushort16_t*)(ws + 80000000); // 3.2M (edge ids, u16)
  int*     eoff   = (int*)(ws + 86400000);
  int*     noff   = (int*)(ws + 86600008);
  int*     echunkcnt = (int*)(ws + 87000016);
  int*     nchunkcnt = (int*)(ws + 87611540);
  int*     erunoff   = (int*)(ws + 88223064);
  int*     nrunoff   = (int*)(ws + 88834588);
  int*     ebinbase  = (int*)(ws + 89446112);
  int*     nbinbase  = (int*)(ws + 89447680);
  int*     epart     = (int*)(ws + 89449248);
  int*     npart     = (int*)(ws + 89450272);
  __half*  w1t16     = (__half*)(ws + 89451520); // 32,768 -> end 89,484,288

  hist_w1t_kernel<<<nC + 64, 256, 0, stream>>>(node_idx, edge_idx,
                                               echunkcnt, nchunkcnt, nnz, nC,
                                               W1, w1t16);
  cscan_p1_kernel<<<nbE + nbN, 256, 0, stream>>>(echunkcnt, nchunkcnt,
                                                 epart, npart, Le, Ln, nbE);
  cscan_p2_kernel<<<1, 256, 0, stream>>>(epart, npart, ebinbase, nbinbase,
                                         nbE, nbN, nnz);
  cscan_p3_kernel<<<nbE + nbN, 256, 0, stream>>>(echunkcnt, nchunkcnt,
                                                 epart, npart, erunoff, nrunoff,
                                                 ebinbase, nbinbase, Le, Ln, nbE, nC);
  // stage (391 blocks) + gemm1 (1563 blocks): independent -> one launch
  stage_gemm1_kernel<<<nC + (n_nodes + 63) / 64, 256, 0, stream>>>(
      node_idx, edge_idx, erunoff, nrunoff, epairs, npairs, nnz, nC,
      x, w1t16, xw16, n_nodes);
  bin_scatter_kernel<<<EBINS + NBINS, 256, 0, stream>>>(epairs, npairs,
                                                        ebinbase, nbinbase,
                                                        eoff, noff, enbr, nnbr16,
                                                        n_edges, n_nodes);

  // layer 1 aggregations (fp16 flat message path)
  edge_agg128_kernel<<<(n_edges * 64 + 255) / 256, 256, 0, stream>>>(
      (const f32x4*)xw16, enbr, eoff, (float4*)ef16, n_edges);
  node_agg128_kernel<<<(n_nodes * 64 + 255) / 256, 256, 0, stream>>>(
      (const f32x4*)ef16, nnbr16, noff, b1, (float4*)h16, n_nodes);

  // layer 2
  gemm2_kernel<<<(n_nodes + 511) / 512, 256, 0, stream>>>(h16, W2,
                                                          (__half2*)hw216, n_nodes);
  edge_agg16_kernel<<<(n_edges * 64 + 255) / 256, 256, 0, stream>>>(
      (const unsigned*)hw216, enbr, eoff, ef2, n_edges);
  node_agg16_kernel<<<(n_nodes * 64 + 255) / 256, 256, 0, stream>>>(
      ef2, nnbr16, noff, b2, out, n_nodes);
}